// Round 2
// baseline (1549.479 us; speedup 1.0000x reference)
//
#include <hip/hip_runtime.h>
#include <hip/hip_bf16.h>

#define NTOK 4096
#define DDIM 1024
#define HDIM 4096
#define NEXP 8
#define TM 128
#define TN 128
#define BK 64
#define KSPLIT 2

typedef __attribute__((ext_vector_type(4))) float f32x4;
typedef __attribute__((ext_vector_type(8))) short bf16x8;
typedef __attribute__((ext_vector_type(4))) short bf16x4;

static __device__ __forceinline__ short f2bf(float f) {
  union { __hip_bfloat16 b; short s; } u;
  u.b = __float2bfloat16(f);
  return u.s;
}

// Async global->LDS, 16B per lane. LDS dest must be wave-uniform base; lane i
// lands at base + i*16 (guide §5: wave-uniform base + lane*size, no pad).
static __device__ __forceinline__ void gload16(const short* g, short* l) {
  __builtin_amdgcn_global_load_lds(
      (const __attribute__((address_space(1))) void*)g,
      (__attribute__((address_space(3))) void*)l,
      16, 0, 0);
}

// ---------------- Weight fp32 -> bf16 conversion (once per call) ----------------
__global__ __launch_bounds__(256) void conv_kernel(
    const float* __restrict__ w1, const float* __restrict__ w2,
    const float* __restrict__ w3,
    short* __restrict__ o1, short* __restrict__ o2, short* __restrict__ o3)
{
  const float* s; short* d;
  if (blockIdx.y == 0)      { s = w1; d = o1; }
  else if (blockIdx.y == 1) { s = w2; d = o2; }
  else                      { s = w3; d = o3; }
  const size_t i = ((size_t)blockIdx.x * 256 + threadIdx.x) * 8;
  const f32x4 a = *(const f32x4*)(s + i);
  const f32x4 b = *(const f32x4*)(s + i + 4);
  bf16x8 r = { f2bf(a[0]), f2bf(a[1]), f2bf(a[2]), f2bf(a[3]),
               f2bf(b[0]), f2bf(b[1]), f2bf(b[2]), f2bf(b[3]) };
  *(bf16x8*)(d + i) = r;
}

// ---------------- Router: one wave per token; also emits xb (bf16 x) ----------------
__global__ __launch_bounds__(256) void router_kernel(
    const float* __restrict__ x, const float* __restrict__ gw,
    const float* __restrict__ rs,
    int* __restrict__ tok_id, float* __restrict__ tok_w,
    int* __restrict__ counts, short* __restrict__ xb)
{
  const int wv = threadIdx.x >> 6;
  const int lane = threadIdx.x & 63;
  const int tok = blockIdx.x * 4 + wv;
  const f32x4* xr = (const f32x4*)(x + (size_t)tok * DDIM);
  f32x4 xv[4];
#pragma unroll
  for (int j = 0; j < 4; ++j) xv[j] = xr[j * 64 + lane];
  // bf16 copy of x for stage A staging
  short* xbr = xb + (size_t)tok * DDIM;
#pragma unroll
  for (int j = 0; j < 4; ++j) {
    bf16x4 bv = { f2bf(xv[j][0]), f2bf(xv[j][1]), f2bf(xv[j][2]), f2bf(xv[j][3]) };
    *(bf16x4*)(xbr + (j * 64 + lane) * 4) = bv;
  }
  float lg[NEXP];
#pragma unroll
  for (int e = 0; e < NEXP; ++e) {
    const f32x4* gr = (const f32x4*)(gw + (size_t)e * DDIM);
    float s = 0.f;
#pragma unroll
    for (int j = 0; j < 4; ++j) {
      f32x4 g = gr[j * 64 + lane];
      s += g[0]*xv[j][0] + g[1]*xv[j][1] + g[2]*xv[j][2] + g[3]*xv[j][3];
    }
#pragma unroll
    for (int off = 32; off > 0; off >>= 1) s += __shfl_down(s, off, 64);
    lg[e] = s;
  }
  if (lane == 0) {
    const float scale = rs[0];
#pragma unroll
    for (int e = 0; e < NEXP; ++e) lg[e] *= scale;
    int i0 = 0;
#pragma unroll
    for (int e = 1; e < NEXP; ++e) if (lg[e] > lg[i0]) i0 = e;   // first-occurrence max
    int i1 = (i0 == 0) ? 1 : 0;
#pragma unroll
    for (int e = 0; e < NEXP; ++e) if (e != i0 && lg[e] > lg[i1]) i1 = e;
    const float w0 = 1.f / (1.f + expf(lg[i1] - lg[i0]));
    int s0 = atomicAdd(&counts[i0], 1);
    tok_id[i0 * NTOK + s0] = tok;
    tok_w[i0 * NTOK + s0] = w0;
    int s1 = atomicAdd(&counts[i1], 1);
    tok_id[i1 * NTOK + s1] = tok;
    tok_w[i1 * NTOK + s1] = 1.f - w0;
  }
}

// ---------------- Finalize: padded prefix offsets for compacted h ----------------
__global__ void finalize_kernel(const int* __restrict__ counts, int* __restrict__ hoff) {
  if (threadIdx.x == 0) {
    int off = 0;
    for (int e = 0; e < NEXP; ++e) { hoff[e] = off; off += ((counts[e] + TM - 1) / TM) * TM; }
  }
}

// ---------------- Stage A: h = silu(Xe@w1^T + b1) * (Xe@w2^T + b2) ----------------
// LDS tiles unpadded (128B rows) for global_load_lds; XOR chunk swizzle on the
// SOURCE address side keeps ds_read_b128 bank-balanced (2 lanes/bank-group).
__global__ __launch_bounds__(256, 2) void stagea_kernel(
    const short* __restrict__ xb,
    const short* __restrict__ w1b, const float* __restrict__ b1,
    const short* __restrict__ w2b, const float* __restrict__ b2,
    const int* __restrict__ tok_id,
    const int* __restrict__ counts, const int* __restrict__ hoff,
    short* __restrict__ h)
{
  const int e = blockIdx.z;
  const int mt = blockIdx.x;          // x = mt: consecutive blocks share weight tiles
  if (mt * TM >= counts[e]) return;
  const int nt = blockIdx.y;

  __shared__ __align__(16) short sA[TM * BK];    // 16 KB
  __shared__ __align__(16) short sB1[TN * BK];
  __shared__ __align__(16) short sB2[TN * BK];
  __shared__ int srow[TM];

  const int t = threadIdx.x;
  const int lane = t & 63;
  const int wv = t >> 6;
  if (t < TM) {
    int id = tok_id[e * NTOK + mt * TM + t];
    srow[t] = id < 0 ? 0 : id;   // pad rows duplicate token 0; discarded later
  }
  __syncthreads();

  // staging: issue j of wave wv fills LDS bytes [seg*1024, +1024), seg=wv*4+j.
  // lane -> row = seg*8 + lane/8, phys chunk = lane%8; source logical chunk
  // cidx = (lane%8) ^ (row&7) = (lane&7) ^ (lane>>3)  (8 shorts per chunk)
  const int cidx = (lane & 7) ^ (lane >> 3);
  const short* asrc[4]; const short* b1src[4]; const short* b2src[4];
  short* adst[4]; short* b1dst[4]; short* b2dst[4];
  const short* wa = w1b + (size_t)e * HDIM * DDIM + (size_t)(nt * TN) * DDIM;
  const short* wb = w2b + (size_t)e * HDIM * DDIM + (size_t)(nt * TN) * DDIM;
#pragma unroll
  for (int j = 0; j < 4; ++j) {
    const int seg = wv * 4 + j;
    const int row = seg * 8 + (lane >> 3);
    asrc[j]  = xb + (size_t)srow[row] * DDIM + cidx * 8;
    b1src[j] = wa + (size_t)row * DDIM + cidx * 8;
    b2src[j] = wb + (size_t)row * DDIM + cidx * 8;
    adst[j]  = sA  + seg * 512;
    b1dst[j] = sB1 + seg * 512;
    b2dst[j] = sB2 + seg * 512;
  }

  const int wm = (wv >> 1) * 64;
  const int wn = (wv & 1) * 64;
  const int lr = lane & 15;
  const int lq = lane >> 4;

  f32x4 acc1[4][4] = {};
  f32x4 acc2[4][4] = {};

  for (int k0 = 0; k0 < DDIM; k0 += BK) {
    __syncthreads();
#pragma unroll
    for (int j = 0; j < 4; ++j) {
      gload16(asrc[j] + k0, adst[j]);
      gload16(b1src[j] + k0, b1dst[j]);
      gload16(b2src[j] + k0, b2dst[j]);
    }
    __syncthreads();
#pragma unroll
    for (int ks8 = 0; ks8 < 8; ks8 += 4) {   // ks = ks8*8 elements
      bf16x8 af[4], ba[4], bb[4];
#pragma unroll
      for (int mi = 0; mi < 4; ++mi) {
        const int row = wm + mi * 16 + lr;
        af[mi] = *(const bf16x8*)(sA + row * BK + ((lq + ks8) ^ (lr & 7)) * 8);
      }
#pragma unroll
      for (int ni = 0; ni < 4; ++ni) {
        const int row = wn + ni * 16 + lr;
        ba[ni] = *(const bf16x8*)(sB1 + row * BK + ((lq + ks8) ^ (lr & 7)) * 8);
        bb[ni] = *(const bf16x8*)(sB2 + row * BK + ((lq + ks8) ^ (lr & 7)) * 8);
      }
#pragma unroll
      for (int mi = 0; mi < 4; ++mi)
#pragma unroll
        for (int ni = 0; ni < 4; ++ni) {
          acc1[mi][ni] = __builtin_amdgcn_mfma_f32_16x16x32_bf16(af[mi], ba[ni], acc1[mi][ni], 0, 0, 0);
          acc2[mi][ni] = __builtin_amdgcn_mfma_f32_16x16x32_bf16(af[mi], bb[ni], acc2[mi][ni], 0, 0, 0);
        }
    }
  }

  const int hbase = hoff[e] + mt * TM;
#pragma unroll
  for (int ni = 0; ni < 4; ++ni) {
    const int col = nt * TN + wn + ni * 16 + lr;
    const float bb1 = b1[e * HDIM + col];
    const float bb2 = b2[e * HDIM + col];
#pragma unroll
    for (int mi = 0; mi < 4; ++mi) {
#pragma unroll
      for (int r = 0; r < 4; ++r) {
        const int row = wm + mi * 16 + lq * 4 + r;
        const float z1 = acc1[mi][ni][r] + bb1;
        const float z2 = acc2[mi][ni][r] + bb2;
        const float hv = (z1 / (1.f + expf(-z1))) * z2;
        h[(size_t)(hbase + row) * HDIM + col] = f2bf(hv);
      }
    }
  }
}

// ---------------- Stage B: y += weight * (h @ w3^T + b3), split-K=2, atomic scatter --------
__global__ __launch_bounds__(256, 2) void stageb_kernel(
    const short* __restrict__ h,
    const short* __restrict__ w3b, const float* __restrict__ b3,
    const int* __restrict__ tok_id, const float* __restrict__ tok_w,
    const int* __restrict__ counts, const int* __restrict__ hoff,
    float* __restrict__ y)
{
  const int ez = blockIdx.z;
  const int e = ez >> 1, kz = ez & 1;
  const int mt = blockIdx.x;
  if (mt * TM >= counts[e]) return;
  const int nt = blockIdx.y;

  __shared__ __align__(16) short sA[TM * BK];
  __shared__ __align__(16) short sB[TN * BK];

  const int t = threadIdx.x;
  const int lane = t & 63;
  const int wv = t >> 6;
  const int wm = (wv >> 1) * 64;
  const int wn = (wv & 1) * 64;
  const int lr = lane & 15;
  const int lq = lane >> 4;

  const short* hrow = h + (size_t)(hoff[e] + mt * TM) * HDIM;
  const short* wc = w3b + (size_t)e * DDIM * HDIM + (size_t)(nt * TN) * HDIM;

  const int cidx = (lane & 7) ^ (lane >> 3);
  const short* asrc[4]; const short* bsrc[4];
  short* adst[4]; short* bdst[4];
#pragma unroll
  for (int j = 0; j < 4; ++j) {
    const int seg = wv * 4 + j;
    const int row = seg * 8 + (lane >> 3);
    asrc[j] = hrow + (size_t)row * HDIM + cidx * 8;
    bsrc[j] = wc + (size_t)row * HDIM + cidx * 8;
    adst[j] = sA + seg * 512;
    bdst[j] = sB + seg * 512;
  }

  f32x4 acc[4][4] = {};

  const int kbeg = kz * (HDIM / KSPLIT);
  const int kend = kbeg + (HDIM / KSPLIT);
  for (int k0 = kbeg; k0 < kend; k0 += BK) {
    __syncthreads();
#pragma unroll
    for (int j = 0; j < 4; ++j) {
      gload16(asrc[j] + k0, adst[j]);
      gload16(bsrc[j] + k0, bdst[j]);
    }
    __syncthreads();
#pragma unroll
    for (int ks8 = 0; ks8 < 8; ks8 += 4) {
      bf16x8 af[4], bfr[4];
#pragma unroll
      for (int mi = 0; mi < 4; ++mi)
        af[mi] = *(const bf16x8*)(sA + (wm + mi * 16 + lr) * BK + ((lq + ks8) ^ (lr & 7)) * 8);
#pragma unroll
      for (int ni = 0; ni < 4; ++ni)
        bfr[ni] = *(const bf16x8*)(sB + (wn + ni * 16 + lr) * BK + ((lq + ks8) ^ (lr & 7)) * 8);
#pragma unroll
      for (int mi = 0; mi < 4; ++mi)
#pragma unroll
        for (int ni = 0; ni < 4; ++ni)
          acc[mi][ni] = __builtin_amdgcn_mfma_f32_16x16x32_bf16(af[mi], bfr[ni], acc[mi][ni], 0, 0, 0);
    }
  }

#pragma unroll
  for (int ni = 0; ni < 4; ++ni) {
    const int col = nt * TN + wn + ni * 16 + lr;
    const float bb3 = (kz == 0) ? b3[e * DDIM + col] : 0.f;
#pragma unroll
    for (int mi = 0; mi < 4; ++mi) {
#pragma unroll
      for (int r = 0; r < 4; ++r) {
        const int row = mt * TM + wm + mi * 16 + lq * 4 + r;
        const int tok = tok_id[e * NTOK + row];
        if (tok >= 0) {
          const float wgt = tok_w[e * NTOK + row];
          atomicAdd(&y[(size_t)tok * DDIM + col], wgt * (acc[mi][ni][r] + bb3));
        }
      }
    }
  }
}

extern "C" void kernel_launch(void* const* d_in, const int* in_sizes, int n_in,
                              void* d_out, int out_size, void* d_ws, size_t ws_size,
                              hipStream_t stream) {
  const float* x  = (const float*)d_in[0];
  const float* gw = (const float*)d_in[1];
  const float* rs = (const float*)d_in[2];
  const float* w1 = (const float*)d_in[3];
  const float* b1 = (const float*)d_in[4];
  const float* w2 = (const float*)d_in[5];
  const float* b2 = (const float*)d_in[6];
  const float* w3 = (const float*)d_in[7];
  const float* b3 = (const float*)d_in[8];

  char* ws = (char*)d_ws;
  int*   tok_id = (int*)ws;                        // 131072 B
  float* tok_w  = (float*)(ws + 131072);           // 131072 B
  int*   counts = (int*)(ws + 262144);             // 32 B
  int*   hoff   = (int*)(ws + 262176);             // 32 B
  short* xb     = (short*)(ws + 262656);           // 8.39 MB
  short* w1b    = (short*)(ws + 8651264);          // 67.1 MB
  short* w2b    = (short*)(ws + 75760128);         // 67.1 MB
  short* w3b    = (short*)(ws + 142868992);        // 67.1 MB
  short* h      = (short*)(ws + 209977856);        // 75.4 MB (9208 rows max)

  hipMemsetAsync(counts, 0, 32, stream);
  hipMemsetAsync(tok_id, 0xFF, 131072, stream);    // pad token id = -1
  hipMemsetAsync(d_out, 0, (size_t)out_size * sizeof(float), stream);

  conv_kernel<<<dim3((NEXP * HDIM * DDIM) / 2048, 3), dim3(256), 0, stream>>>(
      w1, w2, w3, w1b, w2b, w3b);
  router_kernel<<<dim3(NTOK / 4), dim3(256), 0, stream>>>(x, gw, rs, tok_id, tok_w, counts, xb);
  finalize_kernel<<<dim3(1), dim3(64), 0, stream>>>(counts, hoff);
  stagea_kernel<<<dim3(NTOK / TM, HDIM / TN, NEXP), dim3(256), 0, stream>>>(
      xb, w1b, b1, w2b, b2, tok_id, counts, hoff, h);
  stageb_kernel<<<dim3(NTOK / TM, DDIM / TN, NEXP * KSPLIT), dim3(256), 0, stream>>>(
      h, w3b, b3, tok_id, tok_w, counts, hoff, (float*)d_out);
}